// Round 1
// baseline (475.226 us; speedup 1.0000x reference)
//
#include <hip/hip_runtime.h>

typedef __attribute__((ext_vector_type(8))) short bf16x8;
typedef __attribute__((ext_vector_type(4))) float f32x4;

#define N_NODES 200000
#define N_TRIP  600000
#define NT_TILES (N_TRIP / 16)   // 37500
#define PI_F 3.14159265358979f

__device__ __forceinline__ unsigned short f2bf(float f) {
    unsigned int u = __float_as_uint(f);
    unsigned int r = u + 0x7FFFu + ((u >> 16) & 1u);   // RNE
    return (unsigned short)(r >> 16);
}
__device__ __forceinline__ float bf2f(unsigned short u) {
    return __uint_as_float(((unsigned int)u) << 16);
}
__device__ __forceinline__ float elu(float x) {
    return (x > 0.f) ? x : (__expf(x) - 1.f);
}

// ---------------------------------------------------------------------------
// prep: W0 [768][64] fp32  ->  w0t2 bf16, fragment-ordered:
//   w0t2[((kc*12 + nt)*16 + t)*32 + j] = W0[(s*256 + kc*32 + j)*64 + o]
//   where n = nt*16+t (P column), s = n>>6, o = n&63.
// ---------------------------------------------------------------------------
__global__ void prep_w0(const float* __restrict__ W0, unsigned short* __restrict__ w0t2) {
    int g = blockIdx.x * 256 + threadIdx.x;      // 0 .. 49151
    int j    = g & 31;
    int tt   = (g >> 5) & 15;
    int rest = g >> 9;                           // 0 .. 95
    int nt = rest % 12;
    int kc = rest / 12;
    int n = nt * 16 + tt;
    int s = n >> 6;
    int o = n & 63;
    w0t2[g] = f2bf(W0[(s * 256 + kc * 32 + j) * 64 + o]);
}

// ---------------------------------------------------------------------------
// stage1: P[node][192] = bf16( h[node][0:256] @ W0' )   (bf16 MFMA, fp32 acc)
// Block = 256 thr = 4 waves; block covers 64 node-rows (16 per wave), N=192.
// A-frags straight from global h (fp32 -> bf16 in reg); B-frags from w0t2.
// ---------------------------------------------------------------------------
__global__ __launch_bounds__(256) void stage1(const float* __restrict__ h,
                                              const unsigned short* __restrict__ w0t2,
                                              unsigned short* __restrict__ P) {
    int lane = threadIdx.x & 63;
    int wid  = threadIdx.x >> 6;
    int t = lane & 15, q = lane >> 4;
    int rowbase = blockIdx.x * 64 + wid * 16;

    const float* hrow = h + (size_t)(rowbase + t) * 256 + q * 8;

    f32x4 acc[12];
#pragma unroll
    for (int i = 0; i < 12; ++i) acc[i] = (f32x4){0.f, 0.f, 0.f, 0.f};

    for (int kc = 0; kc < 8; ++kc) {
        float4 a0 = *(const float4*)(hrow + kc * 32);
        float4 a1 = *(const float4*)(hrow + kc * 32 + 4);
        bf16x8 af;
        af[0] = (short)f2bf(a0.x); af[1] = (short)f2bf(a0.y);
        af[2] = (short)f2bf(a0.z); af[3] = (short)f2bf(a0.w);
        af[4] = (short)f2bf(a1.x); af[5] = (short)f2bf(a1.y);
        af[6] = (short)f2bf(a1.z); af[7] = (short)f2bf(a1.w);
        const unsigned short* bbase = w0t2 + (kc * 192 + t) * 32 + q * 8;
#pragma unroll
        for (int nt = 0; nt < 12; ++nt) {
            bf16x8 bfr = *(const bf16x8*)(bbase + nt * 512);
            acc[nt] = __builtin_amdgcn_mfma_f32_16x16x32_bf16(af, bfr, acc[nt], 0, 0, 0);
        }
    }
    // C layout: row = q*4 + r (node within strip), col = t (feature in n-tile)
#pragma unroll
    for (int nt = 0; nt < 12; ++nt) {
#pragma unroll
        for (int r = 0; r < 4; ++r) {
            int row = rowbase + q * 4 + r;
            P[(size_t)row * 192 + nt * 16 + t] = f2bf(acc[nt][r]);
        }
    }
}

// ---------------------------------------------------------------------------
// stage2: per-triplet MLP. One wave handles 16 triplets per tile iteration.
// z kept in MFMA B-layout; layer GEMMs D = W^T * z^T (A = W^T from LDS).
// C->B layout transform through a per-wave LDS buffer (stride 72 = benign banks).
// ---------------------------------------------------------------------------
__global__ __launch_bounds__(256) void stage2(
    const unsigned short* __restrict__ P, const int* __restrict__ idxs,
    const float* __restrict__ b0,
    const float* __restrict__ Ws, const float* __restrict__ bs,
    const float* __restrict__ W1, const float* __restrict__ b1,
    const float* __restrict__ W2, const float* __restrict__ b2,
    const float* __restrict__ W3, const float* __restrict__ b3,
    const float* __restrict__ W4, const float* __restrict__ b4,
    float* __restrict__ out)
{
    __shared__ unsigned short Wt[4][64][72];   // W^T bf16, [layer][m=out][k=in]
    __shared__ float biasS[4][64];             // bs, b1, b2, b3
    __shared__ float b0S[64];
    __shared__ float W4S[128];                 // W4 [64][2] row-major
    __shared__ float b4S[2];
    __shared__ unsigned short zb[4][16][72];   // per-wave transform buffer

    int tid = threadIdx.x;
    const float* wsrc[4] = {Ws, W1, W2, W3};
    const float* bsrc[4] = {bs, b1, b2, b3};
#pragma unroll
    for (int l = 0; l < 4; ++l) {
        for (int i = 0; i < 16; ++i) {
            int e = i * 256 + tid;             // e = k*64 + m
            int k = e >> 6, m = e & 63;
            Wt[l][m][k] = f2bf(wsrc[l][e]);
        }
        if (tid < 64) biasS[l][tid] = bsrc[l][tid];
    }
    if (tid < 64)  b0S[tid] = b0[tid];
    if (tid < 128) W4S[tid] = W4[tid];
    if (tid < 2)   b4S[tid] = b4[tid];
    __syncthreads();

    int lane = tid & 63, wid = tid >> 6;
    int t = lane & 15, q = lane >> 4;
    unsigned short* myz = &zb[wid][0][0];
    unsigned short* zwp = myz + t * 72 + 4 * q;        // C-layout write base
    const unsigned short* zrp = myz + t * 72 + 8 * q;  // B-frag read base

    // layer GEMM: acc[mt] = (W^T)[mt-tile] * B   (K = 64 in two 32-chunks)
    auto gemmL = [&](int L, bf16x8 bA, bf16x8 bB, f32x4* accout) {
#pragma unroll
        for (int mt = 0; mt < 4; ++mt) {
            f32x4 a = (f32x4){0.f, 0.f, 0.f, 0.f};
            bf16x8 wa = *(const bf16x8*)&Wt[L][mt * 16 + t][q * 8];
            bf16x8 wb = *(const bf16x8*)&Wt[L][mt * 16 + t][32 + q * 8];
            a = __builtin_amdgcn_mfma_f32_16x16x32_bf16(wa, bA, a, 0, 0, 0);
            a = __builtin_amdgcn_mfma_f32_16x16x32_bf16(wb, bB, a, 0, 0, 0);
            accout[mt] = a;
        }
    };
    // C-layout fp32 act -> bf16 B-frags via LDS round trip
    auto c2b = [&](f32x4* act, bf16x8* bfr) {
#pragma unroll
        for (int mt = 0; mt < 4; ++mt) {
            ushort4 pk;
            pk.x = f2bf(act[mt][0]); pk.y = f2bf(act[mt][1]);
            pk.z = f2bf(act[mt][2]); pk.w = f2bf(act[mt][3]);
            *(ushort4*)(zwp + mt * 16) = pk;
        }
        asm volatile("s_waitcnt lgkmcnt(0)" ::: "memory");
        bfr[0] = *(const bf16x8*)(zrp);
        bfr[1] = *(const bf16x8*)(zrp + 32);
    };

    for (int tile = blockIdx.x * 4 + wid; tile < NT_TILES; tile += gridDim.x * 4) {
        int trip = tile * 16 + t;
        int i0 = idxs[trip * 3 + 0];
        int i1 = idxs[trip * 3 + 1];
        int i2 = idxs[trip * 3 + 2];
        const unsigned short* p0p = P + (size_t)i0 * 192 + 8 * q;
        const unsigned short* p1p = P + (size_t)i1 * 192 + 64 + 8 * q;
        const unsigned short* p2p = P + (size_t)i2 * 192 + 128 + 8 * q;

        // z = elu(P0[i0] + P1[i1] + P2[i2] + b0), built directly in B-layout
        bf16x8 zB[2];
#pragma unroll
        for (int c = 0; c < 2; ++c) {
            bf16x8 v0 = *(const bf16x8*)(p0p + 32 * c);
            bf16x8 v1 = *(const bf16x8*)(p1p + 32 * c);
            bf16x8 v2 = *(const bf16x8*)(p2p + 32 * c);
            float4 bb0 = *(const float4*)&b0S[32 * c + 8 * q];
            float4 bb1 = *(const float4*)&b0S[32 * c + 8 * q + 4];
#pragma unroll
            for (int j = 0; j < 8; ++j) {
                float bj = (j < 4) ? ((const float*)&bb0)[j] : ((const float*)&bb1)[j - 4];
                float x = bf2f((unsigned short)v0[j]) + bf2f((unsigned short)v1[j])
                        + bf2f((unsigned short)v2[j]) + bj;
                zB[c][j] = (short)f2bf(elu(x));
            }
        }

        f32x4 tsa[4], ta[4];
        gemmL(0, zB[0], zB[1], tsa);   // ts = z @ Ws  (bias later)
        gemmL(1, zB[0], zB[1], ta);    // t1 = z @ W1

        // a1 = elu(t1 + b1)
#pragma unroll
        for (int mt = 0; mt < 4; ++mt) {
            float4 bv = *(const float4*)&biasS[1][mt * 16 + 4 * q];
#pragma unroll
            for (int r = 0; r < 4; ++r)
                ta[mt][r] = elu(ta[mt][r] + ((const float*)&bv)[r]);
        }
        bf16x8 aB[2];
        c2b(ta, aB);
        gemmL(2, aB[0], aB[1], ta);    // t2 = a1 @ W2

        // z2 = elu(ts + bs + t2 + b2)
#pragma unroll
        for (int mt = 0; mt < 4; ++mt) {
            float4 bv0 = *(const float4*)&biasS[0][mt * 16 + 4 * q];
            float4 bv2 = *(const float4*)&biasS[2][mt * 16 + 4 * q];
#pragma unroll
            for (int r = 0; r < 4; ++r)
                ta[mt][r] = elu(tsa[mt][r] + ((const float*)&bv0)[r]
                              + ta[mt][r]  + ((const float*)&bv2)[r]);
        }
        c2b(ta, aB);
        gemmL(3, aB[0], aB[1], ta);    // z2 @ W3

        // z3 = elu(. + b3); coeffs = z3 @ W4 + b4 via VALU + quad reduce
        float pp0 = 0.f, pp1 = 0.f;
#pragma unroll
        for (int mt = 0; mt < 4; ++mt) {
            float4 bv  = *(const float4*)&biasS[3][mt * 16 + 4 * q];
            float4 w4a = *(const float4*)&W4S[(mt * 16 + 4 * q) * 2];
            float4 w4b = *(const float4*)&W4S[(mt * 16 + 4 * q) * 2 + 4];
#pragma unroll
            for (int r = 0; r < 4; ++r) {
                float x = elu(ta[mt][r] + ((const float*)&bv)[r]);
                float w40 = (r == 0) ? w4a.x : (r == 1) ? w4a.z : (r == 2) ? w4b.x : w4b.z;
                float w41 = (r == 0) ? w4a.y : (r == 1) ? w4a.w : (r == 2) ? w4b.y : w4b.w;
                pp0 += x * w40;
                pp1 += x * w41;
            }
        }
        pp0 += __shfl_xor(pp0, 16); pp0 += __shfl_xor(pp0, 32);
        pp1 += __shfl_xor(pp1, 16); pp1 += __shfl_xor(pp1, 32);
        if (q == 0) {
            float c0 = pp0 + b4S[0];
            float c1 = pp1 + b4S[1];
            float eq = PI_F / (1.f + __expf(-c0 * (0.1f / PI_F)));
            float kk = 50.f * elu(c1 + 2.4f);
            float2 o2; o2.x = eq; o2.y = kk;
            *(float2*)(out + (size_t)trip * 2) = o2;
        }
    }
}

extern "C" void kernel_launch(void* const* d_in, const int* in_sizes, int n_in,
                              void* d_out, int out_size, void* d_ws, size_t ws_size,
                              hipStream_t stream) {
    const float* h  = (const float*)d_in[0];
    const int* idxs = (const int*)d_in[1];
    const float* W0 = (const float*)d_in[2];
    const float* b0 = (const float*)d_in[3];
    const float* Ws = (const float*)d_in[4];
    const float* bs = (const float*)d_in[5];
    const float* W1 = (const float*)d_in[6];
    const float* b1 = (const float*)d_in[7];
    const float* W2 = (const float*)d_in[8];
    const float* b2 = (const float*)d_in[9];
    const float* W3 = (const float*)d_in[10];
    const float* b3 = (const float*)d_in[11];
    const float* W4 = (const float*)d_in[12];
    const float* b4 = (const float*)d_in[13];
    float* out = (float*)d_out;

    unsigned short* P    = (unsigned short*)d_ws;            // 200000*192 bf16 = 76.8 MB
    unsigned short* w0t2 = P + (size_t)N_NODES * 192;        // 49152 bf16

    prep_w0<<<192, 256, 0, stream>>>(W0, w0t2);
    stage1<<<N_NODES / 64, 256, 0, stream>>>(h, w0t2, P);
    stage2<<<1024, 256, 0, stream>>>(P, idxs, b0, Ws, bs, W1, b1, W2, b2, W3, b3, W4, b4, out);
}

// Round 2
// 385.736 us; speedup vs baseline: 1.2320x; 1.2320x over previous
//
#include <hip/hip_runtime.h>
#include <hip/hip_bf16.h>

typedef __attribute__((ext_vector_type(8))) short bf16x8;
typedef __attribute__((ext_vector_type(4))) float f32x4;

#define N_NODES 200000
#define N_STRIPS (N_NODES / 16)      // 12500
#define N_TRIP  600000
#define NPAIRS  (N_TRIP / 32)        // 18750 pairs of 16-triplet tiles
#define PI_F 3.14159265358979f
#define S1_RS 264                    // stage1 LDS row stride (shorts): 256 + 8 pad

__device__ __forceinline__ unsigned short f2bf(float f) {
    unsigned int u = __float_as_uint(f);
    unsigned int r = u + 0x7FFFu + ((u >> 16) & 1u);   // RNE
    return (unsigned short)(r >> 16);
}
__device__ __forceinline__ float bf2f(unsigned short u) {
    return __uint_as_float(((unsigned int)u) << 16);
}
__device__ __forceinline__ float elu(float x) {
    return (x > 0.f) ? x : (__expf(x) - 1.f);
}
__device__ __forceinline__ unsigned int f2bf2(float x, float y) {
    union { __hip_bfloat162 b; unsigned int u; } cv;
    cv.b = __float22bfloat162_rn(make_float2(x, y));   // v_cvt_pk_bf16_f32, RNE
    return cv.u;                                        // low16 = x, high16 = y
}

// ---------------------------------------------------------------------------
// prep: W0 [768][64] fp32 -> w0t2 bf16 fragment-ordered:
//   w0t2[((kc*12 + nt)*16 + t)*32 + j] = W0[(s*256 + kc*32 + j)*64 + o],
//   n = nt*16+t, s = n>>6, o = n&63.
// ---------------------------------------------------------------------------
__global__ void prep_w0(const float* __restrict__ W0, unsigned short* __restrict__ w0t2) {
    int g = blockIdx.x * 256 + threadIdx.x;      // 0 .. 49151
    int j    = g & 31;
    int tt   = (g >> 5) & 15;
    int rest = g >> 9;
    int nt = rest % 12;
    int kc = rest / 12;
    int n = nt * 16 + tt;
    int s = n >> 6;
    int o = n & 63;
    w0t2[g] = f2bf(W0[(s * 256 + kc * 32 + j) * 64 + o]);
}

// ---------------------------------------------------------------------------
// stage1: P[node][192] = bf16(h[node][:] @ W0')
// B register-resident (wave w owns nt = 3w..3w+2: 24 bf16x8 = 96 VGPR, loaded
// once). A streamed through double-buffered LDS strip (16 rows x 264 bf16),
// coalesced float4 global loads issued one strip ahead. 1 barrier / strip.
// ---------------------------------------------------------------------------
__global__ __launch_bounds__(256) void stage1(const float* __restrict__ h,
                                              const unsigned short* __restrict__ w0t2,
                                              unsigned short* __restrict__ P) {
    __shared__ unsigned short A[2][16 * S1_RS];   // 2 x 8448 B
    int tid = threadIdx.x;
    int lane = tid & 63, wid = tid >> 6;
    int t = lane & 15, q = lane >> 4;

    // resident B fragments
    bf16x8 Bf[8][3];
#pragma unroll
    for (int kc = 0; kc < 8; ++kc)
#pragma unroll
        for (int i = 0; i < 3; ++i)
            Bf[kc][i] = *(const bf16x8*)(w0t2 + (size_t)((kc * 12 + wid * 3 + i) * 16 + t) * 32 + q * 8);

    int s = blockIdx.x;
    float4 R[4];
    {
        const float4* src = (const float4*)(h + (size_t)s * 4096);
#pragma unroll
        for (int p4 = 0; p4 < 4; ++p4) R[p4] = src[p4 * 256 + tid];
    }
    int buf = 0;
    while (s < N_STRIPS) {
        // stage current strip: cvt fp32->bf16, write LDS (row = p4*4+wid, col = lane*4)
#pragma unroll
        for (int p4 = 0; p4 < 4; ++p4) {
            uint2 pk;
            pk.x = f2bf2(R[p4].x, R[p4].y);
            pk.y = f2bf2(R[p4].z, R[p4].w);
            *(uint2*)&A[buf][(p4 * 4 + wid) * S1_RS + lane * 4] = pk;
        }
        __syncthreads();
        // prefetch next strip into regs (in flight during compute)
        int snext = s + gridDim.x;
        if (snext < N_STRIPS) {
            const float4* src = (const float4*)(h + (size_t)snext * 4096);
#pragma unroll
            for (int p4 = 0; p4 < 4; ++p4) R[p4] = src[p4 * 256 + tid];
        }
        // compute 16x48 output tile per wave
        f32x4 acc[3];
#pragma unroll
        for (int i = 0; i < 3; ++i) acc[i] = (f32x4){0.f, 0.f, 0.f, 0.f};
        const unsigned short* ab = &A[buf][t * S1_RS + q * 8];
#pragma unroll
        for (int kc = 0; kc < 8; ++kc) {
            bf16x8 af = *(const bf16x8*)(ab + kc * 32);
            acc[0] = __builtin_amdgcn_mfma_f32_16x16x32_bf16(af, Bf[kc][0], acc[0], 0, 0, 0);
            acc[1] = __builtin_amdgcn_mfma_f32_16x16x32_bf16(af, Bf[kc][1], acc[1], 0, 0, 0);
            acc[2] = __builtin_amdgcn_mfma_f32_16x16x32_bf16(af, Bf[kc][2], acc[2], 0, 0, 0);
        }
        // C layout: row = q*4+r, col = t (within nt tile)
#pragma unroll
        for (int i = 0; i < 3; ++i)
#pragma unroll
            for (int r = 0; r < 4; ++r)
                P[(size_t)(s * 16 + q * 4 + r) * 192 + (wid * 3 + i) * 16 + t] = f2bf(acc[i][r]);
        s = snext;
        buf ^= 1;
    }
}

// ---------------------------------------------------------------------------
// stage2: per-triplet MLP, dual-tile per wave (shares W ds_reads between two
// independent chains), gather prefetched one pair ahead, idx two ahead.
// ---------------------------------------------------------------------------
struct I3 { int a, b, c; };

__global__ __launch_bounds__(256) void stage2(
    const unsigned short* __restrict__ P, const int* __restrict__ idxs,
    const float* __restrict__ b0,
    const float* __restrict__ Ws, const float* __restrict__ bs,
    const float* __restrict__ W1, const float* __restrict__ b1,
    const float* __restrict__ W2, const float* __restrict__ b2,
    const float* __restrict__ W3, const float* __restrict__ b3,
    const float* __restrict__ W4, const float* __restrict__ b4,
    float* __restrict__ out)
{
    __shared__ unsigned short Wt[4][64][72];     // W^T bf16 [layer][m][k]
    __shared__ float bC[3][64];                  // 0:b1  1:bs+b2  2:b3
    __shared__ float b0S[64];
    __shared__ float W4S[128];
    __shared__ float b4S[2];
    __shared__ unsigned short zb[4][2][16][72];  // per-wave, per-tile transform buf

    int tid = threadIdx.x;
    {
        const float* wsrc[4] = {Ws, W1, W2, W3};
#pragma unroll
        for (int l = 0; l < 4; ++l)
            for (int i = 0; i < 16; ++i) {
                int e = i * 256 + tid;
                int k = e >> 6, m = e & 63;
                Wt[l][m][k] = f2bf(wsrc[l][e]);
            }
        if (tid < 64) {
            bC[0][tid] = b1[tid];
            bC[1][tid] = bs[tid] + b2[tid];
            bC[2][tid] = b3[tid];
            b0S[tid] = b0[tid];
        }
        if (tid < 128) W4S[tid] = W4[tid];
        if (tid < 2)   b4S[tid] = b4[tid];
    }
    __syncthreads();

    int lane = tid & 63, wid = tid >> 6;
    int t = lane & 15, q = lane >> 4;

    unsigned short* zbase = &zb[wid][0][0][0];
    unsigned short* zwA = zbase + t * 72 + 4 * q;
    const unsigned short* zrA = zbase + t * 72 + 8 * q;
    unsigned short* zwB = zwA + 16 * 72;
    const unsigned short* zrB = zrA + 16 * 72;

    auto loadIdx = [&](int p, I3& A, I3& B) {
        int tripA = p * 32 + t;
        A.a = idxs[tripA * 3 + 0]; A.b = idxs[tripA * 3 + 1]; A.c = idxs[tripA * 3 + 2];
        int tripB = tripA + 16;
        B.a = idxs[tripB * 3 + 0]; B.b = idxs[tripB * 3 + 1]; B.c = idxs[tripB * 3 + 2];
    };
    auto loadFrags = [&](const I3& iA, const I3& iB, bf16x8* fr) {
        const unsigned short* a0 = P + (size_t)iA.a * 192 + 8 * q;
        const unsigned short* a1 = P + (size_t)iA.b * 192 + 64 + 8 * q;
        const unsigned short* a2 = P + (size_t)iA.c * 192 + 128 + 8 * q;
        fr[0] = *(const bf16x8*)(a0);  fr[1] = *(const bf16x8*)(a0 + 32);
        fr[2] = *(const bf16x8*)(a1);  fr[3] = *(const bf16x8*)(a1 + 32);
        fr[4] = *(const bf16x8*)(a2);  fr[5] = *(const bf16x8*)(a2 + 32);
        const unsigned short* c0 = P + (size_t)iB.a * 192 + 8 * q;
        const unsigned short* c1 = P + (size_t)iB.b * 192 + 64 + 8 * q;
        const unsigned short* c2 = P + (size_t)iB.c * 192 + 128 + 8 * q;
        fr[6] = *(const bf16x8*)(c0);  fr[7] = *(const bf16x8*)(c0 + 32);
        fr[8] = *(const bf16x8*)(c1);  fr[9] = *(const bf16x8*)(c1 + 32);
        fr[10] = *(const bf16x8*)(c2); fr[11] = *(const bf16x8*)(c2 + 32);
    };
    auto buildZ = [&](const bf16x8* fr, bf16x8* z) {
#pragma unroll
        for (int c = 0; c < 2; ++c) {
            bf16x8 v0 = fr[0 + c], v1 = fr[2 + c], v2 = fr[4 + c];
            float4 bb0 = *(const float4*)&b0S[32 * c + 8 * q];
            float4 bb1 = *(const float4*)&b0S[32 * c + 8 * q + 4];
#pragma unroll
            for (int j = 0; j < 8; ++j) {
                float bj = (j < 4) ? ((const float*)&bb0)[j] : ((const float*)&bb1)[j - 4];
                float x = bf2f((unsigned short)v0[j]) + bf2f((unsigned short)v1[j])
                        + bf2f((unsigned short)v2[j]) + bj;
                z[c][j] = (short)f2bf(elu(x));
            }
        }
    };
    // dual GEMM: one W fragment pair feeds both tiles' MFMAs
    auto gemmDual = [&](int L, const bf16x8* zA, const bf16x8* zB2, f32x4* aA, f32x4* aB) {
#pragma unroll
        for (int mt = 0; mt < 4; ++mt) {
            bf16x8 wa = *(const bf16x8*)&Wt[L][mt * 16 + t][q * 8];
            bf16x8 wb = *(const bf16x8*)&Wt[L][mt * 16 + t][32 + q * 8];
            f32x4 x = (f32x4){0.f, 0.f, 0.f, 0.f};
            x = __builtin_amdgcn_mfma_f32_16x16x32_bf16(wa, zA[0], x, 0, 0, 0);
            x = __builtin_amdgcn_mfma_f32_16x16x32_bf16(wb, zA[1], x, 0, 0, 0);
            aA[mt] = x;
            f32x4 y = (f32x4){0.f, 0.f, 0.f, 0.f};
            y = __builtin_amdgcn_mfma_f32_16x16x32_bf16(wa, zB2[0], y, 0, 0, 0);
            y = __builtin_amdgcn_mfma_f32_16x16x32_bf16(wb, zB2[1], y, 0, 0, 0);
            aB[mt] = y;
        }
    };
    // C-layout fp32 -> bf16 B-frags via LDS, both tiles, one wait
    auto c2bDual = [&](f32x4* actA, f32x4* actB, bf16x8* oA, bf16x8* oB) {
#pragma unroll
        for (int mt = 0; mt < 4; ++mt) {
            ushort4 pa, pb;
            pa.x = f2bf(actA[mt][0]); pa.y = f2bf(actA[mt][1]);
            pa.z = f2bf(actA[mt][2]); pa.w = f2bf(actA[mt][3]);
            pb.x = f2bf(actB[mt][0]); pb.y = f2bf(actB[mt][1]);
            pb.z = f2bf(actB[mt][2]); pb.w = f2bf(actB[mt][3]);
            *(ushort4*)(zwA + mt * 16) = pa;
            *(ushort4*)(zwB + mt * 16) = pb;
        }
        asm volatile("s_waitcnt lgkmcnt(0)" ::: "memory");
        oA[0] = *(const bf16x8*)(zrA); oA[1] = *(const bf16x8*)(zrA + 32);
        oB[0] = *(const bf16x8*)(zrB); oB[1] = *(const bf16x8*)(zrB + 32);
    };
    auto epi = [&](f32x4* ta, int trip) {
        float pp0 = 0.f, pp1 = 0.f;
#pragma unroll
        for (int mt = 0; mt < 4; ++mt) {
            float4 bv  = *(const float4*)&bC[2][mt * 16 + 4 * q];
            float4 w4a = *(const float4*)&W4S[(mt * 16 + 4 * q) * 2];
            float4 w4b = *(const float4*)&W4S[(mt * 16 + 4 * q) * 2 + 4];
#pragma unroll
            for (int r = 0; r < 4; ++r) {
                float x = elu(ta[mt][r] + ((const float*)&bv)[r]);
                float w40 = (r == 0) ? w4a.x : (r == 1) ? w4a.z : (r == 2) ? w4b.x : w4b.z;
                float w41 = (r == 0) ? w4a.y : (r == 1) ? w4a.w : (r == 2) ? w4b.y : w4b.w;
                pp0 += x * w40;
                pp1 += x * w41;
            }
        }
        pp0 += __shfl_xor(pp0, 16); pp0 += __shfl_xor(pp0, 32);
        pp1 += __shfl_xor(pp1, 16); pp1 += __shfl_xor(pp1, 32);
        if (q == 0) {
            float c0 = pp0 + b4S[0];
            float c1 = pp1 + b4S[1];
            float2 o2;
            o2.x = PI_F / (1.f + __expf(-c0 * (0.1f / PI_F)));
            o2.y = 50.f * elu(c1 + 2.4f);
            *(float2*)(out + (size_t)trip * 2) = o2;
        }
    };

    const int step = gridDim.x * 4;
    int p = blockIdx.x * 4 + wid;
    auto clampP = [&](int x) { return x < NPAIRS ? x : NPAIRS - 1; };

    I3 iA, iB, jA, jB;
    loadIdx(clampP(p), iA, iB);
    bf16x8 fr[12];
    loadFrags(iA, iB, fr);
    loadIdx(clampP(p + step), jA, jB);

    while (p < NPAIRS) {
        bf16x8 zA[2], zB2[2];
        buildZ(fr, zA);
        buildZ(fr + 6, zB2);

        f32x4 sA[4], sB[4], tA_[4], tB_[4];
        gemmDual(0, zA, zB2, sA, sB);      // skip: z @ Ws
        gemmDual(1, zA, zB2, tA_, tB_);    // main: z @ W1

        // prefetch next pair's gathers + idx for pair after that
        int pn = p + step;
        bf16x8 frn[12];
        loadFrags(jA, jB, frn);
        I3 kA, kB;
        loadIdx(clampP(pn + step), kA, kB);

        // a1 = elu(t1 + b1)
#pragma unroll
        for (int mt = 0; mt < 4; ++mt) {
            float4 bv = *(const float4*)&bC[0][mt * 16 + 4 * q];
#pragma unroll
            for (int r = 0; r < 4; ++r) {
                tA_[mt][r] = elu(tA_[mt][r] + ((const float*)&bv)[r]);
                tB_[mt][r] = elu(tB_[mt][r] + ((const float*)&bv)[r]);
            }
        }
        bf16x8 aA[2], aB[2];
        c2bDual(tA_, tB_, aA, aB);
        gemmDual(2, aA, aB, tA_, tB_);     // a1 @ W2

        // z2 = elu(skip + main + (bs+b2))
#pragma unroll
        for (int mt = 0; mt < 4; ++mt) {
            float4 bv = *(const float4*)&bC[1][mt * 16 + 4 * q];
#pragma unroll
            for (int r = 0; r < 4; ++r) {
                tA_[mt][r] = elu(sA[mt][r] + tA_[mt][r] + ((const float*)&bv)[r]);
                tB_[mt][r] = elu(sB[mt][r] + tB_[mt][r] + ((const float*)&bv)[r]);
            }
        }
        c2bDual(tA_, tB_, aA, aB);
        gemmDual(3, aA, aB, tA_, tB_);     // z2 @ W3

        epi(tA_, p * 32 + t);
        epi(tB_, p * 32 + 16 + t);

#pragma unroll
        for (int i = 0; i < 12; ++i) fr[i] = frn[i];
        jA = kA; jB = kB;
        p = pn;
    }
}

extern "C" void kernel_launch(void* const* d_in, const int* in_sizes, int n_in,
                              void* d_out, int out_size, void* d_ws, size_t ws_size,
                              hipStream_t stream) {
    const float* h  = (const float*)d_in[0];
    const int* idxs = (const int*)d_in[1];
    const float* W0 = (const float*)d_in[2];
    const float* b0 = (const float*)d_in[3];
    const float* Ws = (const float*)d_in[4];
    const float* bs = (const float*)d_in[5];
    const float* W1 = (const float*)d_in[6];
    const float* b1 = (const float*)d_in[7];
    const float* W2 = (const float*)d_in[8];
    const float* b2 = (const float*)d_in[9];
    const float* W3 = (const float*)d_in[10];
    const float* b3 = (const float*)d_in[11];
    const float* W4 = (const float*)d_in[12];
    const float* b4 = (const float*)d_in[13];
    float* out = (float*)d_out;

    unsigned short* P    = (unsigned short*)d_ws;         // 200000*192 bf16 = 76.8 MB
    unsigned short* w0t2 = P + (size_t)N_NODES * 192;     // 49152 bf16

    prep_w0<<<192, 256, 0, stream>>>(W0, w0t2);
    stage1<<<512, 256, 0, stream>>>(h, w0t2, P);
    stage2<<<512, 256, 0, stream>>>(P, idxs, b0, Ws, bs, W1, b1, W2, b2, W3, b3, W4, b4, out);
}

// Round 3
// 379.288 us; speedup vs baseline: 1.2529x; 1.0170x over previous
//
#include <hip/hip_runtime.h>
#include <hip/hip_bf16.h>

typedef __attribute__((ext_vector_type(8))) short bf16x8;
typedef __attribute__((ext_vector_type(4))) float f32x4;

#define N_NODES 200000
#define N_STRIPS (N_NODES / 16)      // 12500
#define N_TRIP  600000
#define NPAIRS  (N_TRIP / 32)        // 18750
#define PI_F 3.14159265358979f
#define S1_RS 264                    // stage1 LDS row stride (shorts)

__device__ __forceinline__ unsigned short f2bf(float f) {
    unsigned int u = __float_as_uint(f);
    unsigned int r = u + 0x7FFFu + ((u >> 16) & 1u);   // RNE
    return (unsigned short)(r >> 16);
}
__device__ __forceinline__ float bf2f(unsigned short u) {
    return __uint_as_float(((unsigned int)u) << 16);
}
__device__ __forceinline__ float elu(float x) {
    return (x > 0.f) ? x : (__expf(x) - 1.f);
}
__device__ __forceinline__ unsigned int f2bf2(float x, float y) {
    union { __hip_bfloat162 b; unsigned int u; } cv;
    cv.b = __float22bfloat162_rn(make_float2(x, y));   // v_cvt_pk_bf16_f32
    return cv.u;                                        // low16=x, high16=y
}

// ---------------------------------------------------------------------------
// prep: W0 [768][64] fp32 -> w0t2 bf16 fragment-ordered
// ---------------------------------------------------------------------------
__global__ void prep_w0(const float* __restrict__ W0, unsigned short* __restrict__ w0t2) {
    int g = blockIdx.x * 256 + threadIdx.x;      // 0 .. 49151
    int j    = g & 31;
    int tt   = (g >> 5) & 15;
    int rest = g >> 9;
    int nt = rest % 12;
    int kc = rest / 12;
    int n = nt * 16 + tt;
    int s = n >> 6;
    int o = n & 63;
    w0t2[g] = f2bf(W0[(s * 256 + kc * 32 + j) * 64 + o]);
}

// ---------------------------------------------------------------------------
// stage1: P[node][192] = bf16(h @ W0' + b0/3 per segment)
// B register-resident; A double-buffered through LDS; all 8 A-frags batched
// ahead of the 24 MFMAs per strip.
// ---------------------------------------------------------------------------
__global__ __launch_bounds__(256) void stage1(const float* __restrict__ h,
                                              const unsigned short* __restrict__ w0t2,
                                              const float* __restrict__ b0,
                                              unsigned short* __restrict__ P) {
    __shared__ unsigned short A[2][16 * S1_RS];
    int tid = threadIdx.x;
    int lane = tid & 63, wid = tid >> 6;
    int t = lane & 15, q = lane >> 4;

    bf16x8 Bf[8][3];
#pragma unroll
    for (int kc = 0; kc < 8; ++kc)
#pragma unroll
        for (int i = 0; i < 3; ++i)
            Bf[kc][i] = *(const bf16x8*)(w0t2 + (size_t)((kc * 12 + wid * 3 + i) * 16 + t) * 32 + q * 8);

    float b0v[3];
#pragma unroll
    for (int i = 0; i < 3; ++i) b0v[i] = b0[(wid * 3 + i) * 16 + t] * (1.f / 3.f);

    int s = blockIdx.x;
    float4 R[4];
    {
        const float4* src = (const float4*)(h + (size_t)s * 4096);
#pragma unroll
        for (int p4 = 0; p4 < 4; ++p4) R[p4] = src[p4 * 256 + tid];
    }
    int buf = 0;
    while (s < N_STRIPS) {
#pragma unroll
        for (int p4 = 0; p4 < 4; ++p4) {
            uint2 pk;
            pk.x = f2bf2(R[p4].x, R[p4].y);
            pk.y = f2bf2(R[p4].z, R[p4].w);
            *(uint2*)&A[buf][(p4 * 4 + wid) * S1_RS + lane * 4] = pk;
        }
        __syncthreads();
        int snext = s + gridDim.x;
        if (snext < N_STRIPS) {
            const float4* src = (const float4*)(h + (size_t)snext * 4096);
#pragma unroll
            for (int p4 = 0; p4 < 4; ++p4) R[p4] = src[p4 * 256 + tid];
        }
        // batch all A-frag LDS reads, then MFMA burst
        const unsigned short* ab = &A[buf][t * S1_RS + q * 8];
        bf16x8 af[8];
#pragma unroll
        for (int kc = 0; kc < 8; ++kc) af[kc] = *(const bf16x8*)(ab + kc * 32);

        f32x4 acc[3];
#pragma unroll
        for (int i = 0; i < 3; ++i) acc[i] = (f32x4){0.f, 0.f, 0.f, 0.f};
#pragma unroll
        for (int kc = 0; kc < 8; ++kc) {
            acc[0] = __builtin_amdgcn_mfma_f32_16x16x32_bf16(af[kc], Bf[kc][0], acc[0], 0, 0, 0);
            acc[1] = __builtin_amdgcn_mfma_f32_16x16x32_bf16(af[kc], Bf[kc][1], acc[1], 0, 0, 0);
            acc[2] = __builtin_amdgcn_mfma_f32_16x16x32_bf16(af[kc], Bf[kc][2], acc[2], 0, 0, 0);
        }
#pragma unroll
        for (int i = 0; i < 3; ++i)
#pragma unroll
            for (int r = 0; r < 4; ++r)
                P[(size_t)(s * 16 + q * 4 + r) * 192 + (wid * 3 + i) * 16 + t] = f2bf(acc[i][r] + b0v[i]);
        s = snext;
        buf ^= 1;
    }
}

// ---------------------------------------------------------------------------
// stage2: per-triplet MLP, dual-tile per wave, gather prefetch 1 pair ahead,
// idx 2 ahead; batched Wt reads; packed bf16 converts; b0 pre-folded into P.
// ---------------------------------------------------------------------------
struct I3 { int a, b, c; };

__global__ __launch_bounds__(256) void stage2(
    const unsigned short* __restrict__ P, const int* __restrict__ idxs,
    const float* __restrict__ Ws, const float* __restrict__ bs,
    const float* __restrict__ W1, const float* __restrict__ b1,
    const float* __restrict__ W2, const float* __restrict__ b2,
    const float* __restrict__ W3, const float* __restrict__ b3,
    const float* __restrict__ W4, const float* __restrict__ b4,
    float* __restrict__ out)
{
    __shared__ unsigned short Wt[4][64][72];     // W^T bf16 [layer][m][k]
    __shared__ float bC[3][64];                  // 0:b1  1:bs+b2  2:b3
    __shared__ float W4S[128];
    __shared__ float b4S[2];
    __shared__ unsigned short zb[4][2][16][72];  // per-wave transform buf

    int tid = threadIdx.x;
    {
        const float* wsrc[4] = {Ws, W1, W2, W3};
#pragma unroll
        for (int l = 0; l < 4; ++l)
            for (int i = 0; i < 16; ++i) {
                int e = i * 256 + tid;
                int k = e >> 6, m = e & 63;
                Wt[l][m][k] = f2bf(wsrc[l][e]);
            }
        if (tid < 64) {
            bC[0][tid] = b1[tid];
            bC[1][tid] = bs[tid] + b2[tid];
            bC[2][tid] = b3[tid];
        }
        if (tid < 128) W4S[tid] = W4[tid];
        if (tid < 2)   b4S[tid] = b4[tid];
    }
    __syncthreads();

    int lane = tid & 63, wid = tid >> 6;
    int t = lane & 15, q = lane >> 4;

    unsigned short* zbase = &zb[wid][0][0][0];
    unsigned short* zwA = zbase + t * 72 + 4 * q;
    const unsigned short* zrA = zbase + t * 72 + 8 * q;
    unsigned short* zwB = zwA + 16 * 72;
    const unsigned short* zrB = zrA + 16 * 72;

    auto loadIdx = [&](int p, I3& A, I3& B) {
        int tripA = p * 32 + t;
        A.a = idxs[tripA * 3 + 0]; A.b = idxs[tripA * 3 + 1]; A.c = idxs[tripA * 3 + 2];
        int tripB = tripA + 16;
        B.a = idxs[tripB * 3 + 0]; B.b = idxs[tripB * 3 + 1]; B.c = idxs[tripB * 3 + 2];
    };
    auto loadFrags = [&](const I3& iA, const I3& iB, bf16x8* fr) {
        const unsigned short* a0 = P + (size_t)iA.a * 192 + 8 * q;
        const unsigned short* a1 = P + (size_t)iA.b * 192 + 64 + 8 * q;
        const unsigned short* a2 = P + (size_t)iA.c * 192 + 128 + 8 * q;
        fr[0] = *(const bf16x8*)(a0);  fr[1] = *(const bf16x8*)(a0 + 32);
        fr[2] = *(const bf16x8*)(a1);  fr[3] = *(const bf16x8*)(a1 + 32);
        fr[4] = *(const bf16x8*)(a2);  fr[5] = *(const bf16x8*)(a2 + 32);
        const unsigned short* c0 = P + (size_t)iB.a * 192 + 8 * q;
        const unsigned short* c1 = P + (size_t)iB.b * 192 + 64 + 8 * q;
        const unsigned short* c2 = P + (size_t)iB.c * 192 + 128 + 8 * q;
        fr[6] = *(const bf16x8*)(c0);  fr[7] = *(const bf16x8*)(c0 + 32);
        fr[8] = *(const bf16x8*)(c1);  fr[9] = *(const bf16x8*)(c1 + 32);
        fr[10] = *(const bf16x8*)(c2); fr[11] = *(const bf16x8*)(c2 + 32);
    };
    auto buildZ = [&](const bf16x8* fr, bf16x8* z) {
#pragma unroll
        for (int c = 0; c < 2; ++c) {
            bf16x8 v0 = fr[0 + c], v1 = fr[2 + c], v2 = fr[4 + c];
            float x[8];
#pragma unroll
            for (int j = 0; j < 8; ++j)
                x[j] = elu(bf2f((unsigned short)v0[j]) + bf2f((unsigned short)v1[j])
                         + bf2f((unsigned short)v2[j]));
            union { bf16x8 v; uint4 u; } pk;
            pk.u.x = f2bf2(x[0], x[1]); pk.u.y = f2bf2(x[2], x[3]);
            pk.u.z = f2bf2(x[4], x[5]); pk.u.w = f2bf2(x[6], x[7]);
            z[c] = pk.v;
        }
    };
    // dual GEMM: batch all 8 Wt frag reads, then 16 MFMAs
    auto gemmDual = [&](int L, const bf16x8* zA, const bf16x8* zB2, f32x4* aA, f32x4* aB) {
        bf16x8 wa[4], wb[4];
#pragma unroll
        for (int mt = 0; mt < 4; ++mt) {
            wa[mt] = *(const bf16x8*)&Wt[L][mt * 16 + t][q * 8];
            wb[mt] = *(const bf16x8*)&Wt[L][mt * 16 + t][32 + q * 8];
        }
#pragma unroll
        for (int mt = 0; mt < 4; ++mt) {
            f32x4 x = (f32x4){0.f, 0.f, 0.f, 0.f};
            x = __builtin_amdgcn_mfma_f32_16x16x32_bf16(wa[mt], zA[0], x, 0, 0, 0);
            x = __builtin_amdgcn_mfma_f32_16x16x32_bf16(wb[mt], zA[1], x, 0, 0, 0);
            aA[mt] = x;
            f32x4 y = (f32x4){0.f, 0.f, 0.f, 0.f};
            y = __builtin_amdgcn_mfma_f32_16x16x32_bf16(wa[mt], zB2[0], y, 0, 0, 0);
            y = __builtin_amdgcn_mfma_f32_16x16x32_bf16(wb[mt], zB2[1], y, 0, 0, 0);
            aB[mt] = y;
        }
    };
    auto c2bDual = [&](f32x4* actA, f32x4* actB, bf16x8* oA, bf16x8* oB) {
#pragma unroll
        for (int mt = 0; mt < 4; ++mt) {
            uint2 pa, pb;
            pa.x = f2bf2(actA[mt][0], actA[mt][1]); pa.y = f2bf2(actA[mt][2], actA[mt][3]);
            pb.x = f2bf2(actB[mt][0], actB[mt][1]); pb.y = f2bf2(actB[mt][2], actB[mt][3]);
            *(uint2*)(zwA + mt * 16) = pa;
            *(uint2*)(zwB + mt * 16) = pb;
        }
        asm volatile("s_waitcnt lgkmcnt(0)" ::: "memory");
        oA[0] = *(const bf16x8*)(zrA); oA[1] = *(const bf16x8*)(zrA + 32);
        oB[0] = *(const bf16x8*)(zrB); oB[1] = *(const bf16x8*)(zrB + 32);
    };
    auto epi = [&](f32x4* ta, int trip) {
        float pp0 = 0.f, pp1 = 0.f;
#pragma unroll
        for (int mt = 0; mt < 4; ++mt) {
            float4 bv  = *(const float4*)&bC[2][mt * 16 + 4 * q];
            float4 w4a = *(const float4*)&W4S[(mt * 16 + 4 * q) * 2];
            float4 w4b = *(const float4*)&W4S[(mt * 16 + 4 * q) * 2 + 4];
#pragma unroll
            for (int r = 0; r < 4; ++r) {
                float x = elu(ta[mt][r] + ((const float*)&bv)[r]);
                float w40 = (r == 0) ? w4a.x : (r == 1) ? w4a.z : (r == 2) ? w4b.x : w4b.z;
                float w41 = (r == 0) ? w4a.y : (r == 1) ? w4a.w : (r == 2) ? w4b.y : w4b.w;
                pp0 += x * w40;
                pp1 += x * w41;
            }
        }
        pp0 += __shfl_xor(pp0, 16); pp0 += __shfl_xor(pp0, 32);
        pp1 += __shfl_xor(pp1, 16); pp1 += __shfl_xor(pp1, 32);
        if (q == 0) {
            float c0 = pp0 + b4S[0];
            float c1 = pp1 + b4S[1];
            float2 o2;
            o2.x = PI_F / (1.f + __expf(-c0 * (0.1f / PI_F)));
            o2.y = 50.f * elu(c1 + 2.4f);
            *(float2*)(out + (size_t)trip * 2) = o2;
        }
    };

    const int step = gridDim.x * 4;
    int p = blockIdx.x * 4 + wid;
    auto clampP = [&](int x) { return x < NPAIRS ? x : NPAIRS - 1; };

    I3 iA, iB, jA, jB;
    loadIdx(clampP(p), iA, iB);
    bf16x8 fr[12];
    loadFrags(iA, iB, fr);
    loadIdx(clampP(p + step), jA, jB);

    while (p < NPAIRS) {
        bf16x8 zA[2], zB2[2];
        buildZ(fr, zA);
        buildZ(fr + 6, zB2);

        f32x4 sA[4], sB[4], tA_[4], tB_[4];
        gemmDual(0, zA, zB2, sA, sB);      // skip: z @ Ws
        gemmDual(1, zA, zB2, tA_, tB_);    // main: z @ W1

        int pn = p + step;
        bf16x8 frn[12];
        loadFrags(jA, jB, frn);
        I3 kA, kB;
        loadIdx(clampP(pn + step), kA, kB);

        // a1 = elu(t1 + b1)
#pragma unroll
        for (int mt = 0; mt < 4; ++mt) {
            float4 bv = *(const float4*)&bC[0][mt * 16 + 4 * q];
#pragma unroll
            for (int r = 0; r < 4; ++r) {
                tA_[mt][r] = elu(tA_[mt][r] + ((const float*)&bv)[r]);
                tB_[mt][r] = elu(tB_[mt][r] + ((const float*)&bv)[r]);
            }
        }
        bf16x8 aA[2], aB[2];
        c2bDual(tA_, tB_, aA, aB);
        gemmDual(2, aA, aB, tA_, tB_);     // a1 @ W2

        // z2 = elu(skip + main + (bs+b2))
#pragma unroll
        for (int mt = 0; mt < 4; ++mt) {
            float4 bv = *(const float4*)&bC[1][mt * 16 + 4 * q];
#pragma unroll
            for (int r = 0; r < 4; ++r) {
                tA_[mt][r] = elu(sA[mt][r] + tA_[mt][r] + ((const float*)&bv)[r]);
                tB_[mt][r] = elu(sB[mt][r] + tB_[mt][r] + ((const float*)&bv)[r]);
            }
        }
        c2bDual(tA_, tB_, aA, aB);
        gemmDual(3, aA, aB, tA_, tB_);     // z2 @ W3

        epi(tA_, p * 32 + t);
        epi(tB_, p * 32 + 16 + t);

#pragma unroll
        for (int i = 0; i < 12; ++i) fr[i] = frn[i];
        jA = kA; jB = kB;
        p = pn;
    }
}

extern "C" void kernel_launch(void* const* d_in, const int* in_sizes, int n_in,
                              void* d_out, int out_size, void* d_ws, size_t ws_size,
                              hipStream_t stream) {
    const float* h  = (const float*)d_in[0];
    const int* idxs = (const int*)d_in[1];
    const float* W0 = (const float*)d_in[2];
    const float* b0 = (const float*)d_in[3];
    const float* Ws = (const float*)d_in[4];
    const float* bs = (const float*)d_in[5];
    const float* W1 = (const float*)d_in[6];
    const float* b1 = (const float*)d_in[7];
    const float* W2 = (const float*)d_in[8];
    const float* b2 = (const float*)d_in[9];
    const float* W3 = (const float*)d_in[10];
    const float* b3 = (const float*)d_in[11];
    const float* W4 = (const float*)d_in[12];
    const float* b4 = (const float*)d_in[13];
    float* out = (float*)d_out;

    unsigned short* P    = (unsigned short*)d_ws;         // 200000*192 bf16 = 76.8 MB
    unsigned short* w0t2 = P + (size_t)N_NODES * 192;     // 49152 bf16

    prep_w0<<<192, 256, 0, stream>>>(W0, w0t2);
    stage1<<<512, 256, 0, stream>>>(h, w0t2, b0, P);
    stage2<<<512, 256, 0, stream>>>(P, idxs, Ws, bs, W1, b1, W2, b2, W3, b3, W4, b4, out);
}